// Round 15
// baseline (28.086 us; speedup 1.0000x reference)
//
#include <hip/hip_runtime.h>

#define BATCH 262144
#define NUM_LAYERS 64
#define KB 8   // layers per burst; 8 bursts, double-buffered (WAR-distance fix)

typedef float f32x2 __attribute__((ext_vector_type(2)));
typedef float f32x4 __attribute__((ext_vector_type(4)));

struct SQState {
    f32x2 ur0, ui0, ur1, ui1;   // pre-omega state, lanes = (elem A, elem B)
};

// Compute KB layers, results into named register buffers (NO reuse of the
// buffer that the immediately preceding burst is still storing from -- the
// caller alternates two buffer sets, so the compiler's vmcnt WAR wait before
// overwriting a buffer lands one full compute-phase after its stores issued).
template <int MODE>
__device__ __forceinline__ void burst_compute(
    int l0, const float4* cA, const float2* cOm,
    f32x2 x0, f32x2 x1, SQState& s,
    f32x4 (&bufA)[KB], f32x4 (&bufB)[KB])
{
#pragma unroll
    for (int k = 0; k < KB; ++k) {
        const float4 c = cA[l0 + k];
        const float2 om = cOm[l0 + k];

        const f32x2 hpsiV = x0 * c.x + c.y;
        const f32x2 hthV  = x1 * c.z + c.w;

        float s0, c0, s1, c1, s2, c2, s3, c3;
        __sincosf(hpsiV.x, &s0, &c0);
        __sincosf(hpsiV.y, &s1, &c1);
        __sincosf(hthV.x,  &s2, &c2);
        __sincosf(hthV.y,  &s3, &c3);
        const f32x2 sps = {s0, s1}, cps = {c0, c1};
        const f32x2 sth = {s2, s3}, cth = {c2, c3};

        // Rz(psi): a0 = u0 * (cps - i*sps); a1 = u1 * (cps + i*sps)
        const f32x2 a0r = s.ui0 * sps + s.ur0 * cps;
        const f32x2 a0i = s.ui0 * cps - s.ur0 * sps;
        const f32x2 a1r = s.ur1 * cps - s.ui1 * sps;
        const f32x2 a1i = s.ui1 * cps + s.ur1 * sps;
        // Ry(th)
        s.ur0 = cth * a0r - sth * a1r;
        s.ui0 = cth * a0i - sth * a1i;
        s.ur1 = sth * a0r + cth * a1r;
        s.ui1 = sth * a0i + cth * a1i;

        // store-side Rz(omega): t0 = u0*(co - i so), t1 = u1*(co + i so)
        if (MODE == 0) {
            const f32x2 t0r = s.ui0 * om.y + s.ur0 * om.x;
            const f32x2 t1r = s.ur1 * om.x - s.ui1 * om.y;
            f32x4 v; v.x = t0r.x; v.y = t1r.x; v.z = t0r.y; v.w = t1r.y;
            bufA[k] = v;
        } else {
            const f32x2 t0r = s.ui0 * om.y + s.ur0 * om.x;
            const f32x2 t0i = s.ui0 * om.x - s.ur0 * om.y;
            const f32x2 t1r = s.ur1 * om.x - s.ui1 * om.y;
            const f32x2 t1i = s.ui1 * om.x + s.ur1 * om.y;
            f32x4 va; va.x = t0r.x; va.y = t0i.x; va.z = t1r.x; va.w = t1i.x;
            f32x4 vb; vb.x = t0r.y; vb.y = t0i.y; vb.z = t1r.y; vb.w = t1i.y;
            bufA[k] = va;
            bufB[k] = vb;
        }
    }
}

template <int MODE>
__device__ __forceinline__ void burst_store(
    int l0, int g, f32x4* o4,
    const f32x4 (&bufA)[KB], const f32x4 (&bufB)[KB])
{
    if (MODE == 0) {
#pragma unroll
        for (int k = 0; k < KB; ++k)
            o4[(l0 + k) * (BATCH / 2) + g] = bufA[k];
    } else {
#pragma unroll
        for (int k = 0; k < KB; ++k) {
            o4[((l0 + k) * BATCH + 2 * g) + 0] = bufA[k];
            o4[((l0 + k) * BATCH + 2 * g) + 1] = bufB[k];
        }
    }
}

template <int MODE>
__global__ __launch_bounds__(256) void squbit_kernel(
    const float* __restrict__ X,       // (BATCH, 2)
    const float* __restrict__ W,       // (NUM_LAYERS, 3)
    const float* __restrict__ Bi,      // (NUM_LAYERS, 3)
    float* __restrict__ out)
{
    __shared__ float4 cA[NUM_LAYERS];   // {0.5*w0, 0.5*b0 + hom_prev, 0.5*w1, 0.5*b1}
    __shared__ float2 cOm[NUM_LAYERS];  // {cos(om/2), sin(om/2)}

    const int t = threadIdx.x;
    if (t < NUM_LAYERS) {
        const float w0 = W[t * 3 + 0], w1 = W[t * 3 + 1], w2 = W[t * 3 + 2];
        const float b0 = Bi[t * 3 + 0], b1 = Bi[t * 3 + 1], b2 = Bi[t * 3 + 2];
        float hom_prev = 0.0f;
        if (t > 0) hom_prev = 0.5f * (W[(t - 1) * 3 + 2] + Bi[(t - 1) * 3 + 2]);
        cA[t] = make_float4(0.5f * w0, fmaf(0.5f, b0, hom_prev), 0.5f * w1, 0.5f * b1);
        const float hom = 0.5f * (w2 + b2);
        float so, co;
        __sincosf(hom, &so, &co);
        cOm[t] = make_float2(co, so);
    }
    __syncthreads();

    const int g = blockIdx.x * 256 + t;          // batch elems 2g (A), 2g+1 (B)
    const float4 xx = reinterpret_cast<const float4*>(X)[g];

    const f32x2 x0 = {xx.x, xx.z};   // X[:,0] for A,B
    const f32x2 x1 = {xx.y, xx.w};   // X[:,1] for A,B

    SQState st;
    st.ur0 = {1.0f, 1.0f}; st.ui0 = {0.0f, 0.0f};
    st.ur1 = {0.0f, 0.0f}; st.ui1 = {0.0f, 0.0f};

    f32x4* o4 = reinterpret_cast<f32x4*>(out);

    // Two named buffer sets, alternated: while set P's stores drain, set Q's
    // compute runs. vmcnt WAR wait before re-filling P is ~1 compute phase
    // (~2900 cyc) after P's stores issued (> ~900 cyc store latency).
    f32x4 pA[KB], pB[KB], qA[KB], qB[KB];

    burst_compute<MODE>( 0, cA, cOm, x0, x1, st, pA, pB);
    burst_store<MODE>( 0, g, o4, pA, pB);
    burst_compute<MODE>( 8, cA, cOm, x0, x1, st, qA, qB);
    burst_store<MODE>( 8, g, o4, qA, qB);
    burst_compute<MODE>(16, cA, cOm, x0, x1, st, pA, pB);
    burst_store<MODE>(16, g, o4, pA, pB);
    burst_compute<MODE>(24, cA, cOm, x0, x1, st, qA, qB);
    burst_store<MODE>(24, g, o4, qA, qB);
    burst_compute<MODE>(32, cA, cOm, x0, x1, st, pA, pB);
    burst_store<MODE>(32, g, o4, pA, pB);
    burst_compute<MODE>(40, cA, cOm, x0, x1, st, qA, qB);
    burst_store<MODE>(40, g, o4, qA, qB);
    burst_compute<MODE>(48, cA, cOm, x0, x1, st, pA, pB);
    burst_store<MODE>(48, g, o4, pA, pB);
    burst_compute<MODE>(56, cA, cOm, x0, x1, st, qA, qB);
    burst_store<MODE>(56, g, o4, qA, qB);
}

extern "C" void kernel_launch(void* const* d_in, const int* in_sizes, int n_in,
                              void* d_out, int out_size, void* d_ws, size_t ws_size,
                              hipStream_t stream) {
    const float* X  = (const float*)d_in[0];
    const float* W  = (const float*)d_in[1];
    const float* Bi = (const float*)d_in[2];
    float* out = (float*)d_out;

    dim3 grid(BATCH / 512), block(256);   // 2 batch elems per thread

    const long long full_complex_floats = (long long)NUM_LAYERS * BATCH * 4;
    if ((long long)out_size >= full_complex_floats) {
        squbit_kernel<1><<<grid, block, 0, stream>>>(X, W, Bi, out);
    } else {
        squbit_kernel<0><<<grid, block, 0, stream>>>(X, W, Bi, out);
    }
}

// Round 16
// 26.700 us; speedup vs baseline: 1.0519x; 1.0519x over previous
//
#include <hip/hip_runtime.h>

#define BATCH 262144
#define NUM_LAYERS 64
#define KB 8   // layers per register-accumulated store burst

typedef float f32x2 __attribute__((ext_vector_type(2)));
typedef float f32x4 __attribute__((ext_vector_type(4)));

// FINAL (best measured: 26.73us, R14). R7 math + KB=8 store bursting.
// U(phi,theta,omega) = Rz(omega)*Ry(theta)*Rz(phi); propagate pre-omega state
//   u_l = Ry(theta_l) * Rz(phi_l + omega_{l-1}) * u_{l-1}
// omega is batch-independent (folded into per-layer constants + store-side
// 4-fma Rz(omega)). Two batch elems per thread in packed-f32 lanes
// (v_pk_fma path). One 16B coalesced store per layer per thread.
//
// Perf record (MI355X): steady ~24.7us = 5.5 TB/s effective; same-pattern
// pure-store floor measured at ~18.5us (~7 TB/s, R13 probe); the ~6us
// compute-coexistence cost was invariant under 9 structural variants
// (waves/SIMD 1-4, store width/rate, nt, trans batching, burst/dbuf shapes).
template <int MODE>
__global__ __launch_bounds__(256) void squbit_kernel(
    const float* __restrict__ X,       // (BATCH, 2)
    const float* __restrict__ W,       // (NUM_LAYERS, 3)
    const float* __restrict__ Bi,      // (NUM_LAYERS, 3)
    float* __restrict__ out)
{
    __shared__ float4 cA[NUM_LAYERS];   // {0.5*w0, 0.5*b0 + hom_prev, 0.5*w1, 0.5*b1}
    __shared__ float2 cOm[NUM_LAYERS];  // {cos(om/2), sin(om/2)}

    const int t = threadIdx.x;
    if (t < NUM_LAYERS) {
        const float w0 = W[t * 3 + 0], w1 = W[t * 3 + 1], w2 = W[t * 3 + 2];
        const float b0 = Bi[t * 3 + 0], b1 = Bi[t * 3 + 1], b2 = Bi[t * 3 + 2];
        float hom_prev = 0.0f;
        if (t > 0) hom_prev = 0.5f * (W[(t - 1) * 3 + 2] + Bi[(t - 1) * 3 + 2]);
        cA[t] = make_float4(0.5f * w0, fmaf(0.5f, b0, hom_prev), 0.5f * w1, 0.5f * b1);
        const float hom = 0.5f * (w2 + b2);
        float so, co;
        __sincosf(hom, &so, &co);
        cOm[t] = make_float2(co, so);
    }
    __syncthreads();

    const int g = blockIdx.x * 256 + t;          // batch elems 2g (A), 2g+1 (B)
    const float4 xx = reinterpret_cast<const float4*>(X)[g];

    const f32x2 x0 = {xx.x, xx.z};   // X[:,0] for A,B
    const f32x2 x1 = {xx.y, xx.w};   // X[:,1] for A,B

    // pre-omega state, lanes = (A,B)
    f32x2 ur0 = {1.0f, 1.0f}, ui0 = {0.0f, 0.0f};
    f32x2 ur1 = {0.0f, 0.0f}, ui1 = {0.0f, 0.0f};

    f32x4* o4 = reinterpret_cast<f32x4*>(out);

    for (int l0 = 0; l0 < NUM_LAYERS; l0 += KB) {
        f32x4 bufA[KB];     // MODE0: packed (t0r.A, t1r.A, t0r.B, t1r.B)
        f32x4 bufB[KB];     // MODE1 second half (only used there)

        #pragma unroll
        for (int k = 0; k < KB; ++k) {
            const int l = l0 + k;
            const float4 c = cA[l];
            const float2 om = cOm[l];

            const f32x2 hpsiV = x0 * c.x + c.y;
            const f32x2 hthV  = x1 * c.z + c.w;

            float s0, c0, s1, c1, s2, c2, s3, c3;
            __sincosf(hpsiV.x, &s0, &c0);
            __sincosf(hpsiV.y, &s1, &c1);
            __sincosf(hthV.x,  &s2, &c2);
            __sincosf(hthV.y,  &s3, &c3);
            const f32x2 sps = {s0, s1}, cps = {c0, c1};
            const f32x2 sth = {s2, s3}, cth = {c2, c3};

            // Rz(psi): a0 = u0 * (cps - i*sps); a1 = u1 * (cps + i*sps)
            const f32x2 a0r = ui0 * sps + ur0 * cps;
            const f32x2 a0i = ui0 * cps - ur0 * sps;
            const f32x2 a1r = ur1 * cps - ui1 * sps;
            const f32x2 a1i = ui1 * cps + ur1 * sps;
            // Ry(th)
            ur0 = cth * a0r - sth * a1r;
            ui0 = cth * a0i - sth * a1i;
            ur1 = sth * a0r + cth * a1r;
            ui1 = sth * a0i + cth * a1i;

            // store-side Rz(omega): t0 = u0*(co - i so), t1 = u1*(co + i so)
            if (MODE == 0) {
                const f32x2 t0r = ui0 * om.y + ur0 * om.x;
                const f32x2 t1r = ur1 * om.x - ui1 * om.y;
                f32x4 v; v.x = t0r.x; v.y = t1r.x; v.z = t0r.y; v.w = t1r.y;
                bufA[k] = v;
            } else {
                const f32x2 t0r = ui0 * om.y + ur0 * om.x;
                const f32x2 t0i = ui0 * om.x - ur0 * om.y;
                const f32x2 t1r = ur1 * om.x - ui1 * om.y;
                const f32x2 t1i = ui1 * om.x + ur1 * om.y;
                f32x4 va; va.x = t0r.x; va.y = t0i.x; va.z = t1r.x; va.w = t1i.x;
                f32x4 vb; vb.x = t0r.y; vb.y = t0i.y; vb.z = t1r.y; vb.w = t1i.y;
                bufA[k] = va;
                bufB[k] = vb;
            }
        }

        // burst store: KB back-to-back 16B stores
        if (MODE == 0) {
            #pragma unroll
            for (int k = 0; k < KB; ++k) {
                o4[(l0 + k) * (BATCH / 2) + g] = bufA[k];
            }
        } else {
            #pragma unroll
            for (int k = 0; k < KB; ++k) {
                o4[((l0 + k) * BATCH + 2 * g) + 0] = bufA[k];
                o4[((l0 + k) * BATCH + 2 * g) + 1] = bufB[k];
            }
        }
    }
}

extern "C" void kernel_launch(void* const* d_in, const int* in_sizes, int n_in,
                              void* d_out, int out_size, void* d_ws, size_t ws_size,
                              hipStream_t stream) {
    const float* X  = (const float*)d_in[0];
    const float* W  = (const float*)d_in[1];
    const float* Bi = (const float*)d_in[2];
    float* out = (float*)d_out;

    dim3 grid(BATCH / 512), block(256);   // 2 batch elems per thread

    const long long full_complex_floats = (long long)NUM_LAYERS * BATCH * 4;
    if ((long long)out_size >= full_complex_floats) {
        squbit_kernel<1><<<grid, block, 0, stream>>>(X, W, Bi, out);
    } else {
        squbit_kernel<0><<<grid, block, 0, stream>>>(X, W, Bi, out);
    }
}